// Round 1
// baseline (10688.971 us; speedup 1.0000x reference)
//
#include <hip/hip_runtime.h>
#include <cstdint>
#include <cstddef>

// ---- problem constants ----
#define S_ 256
#define B_ 8
#define V_ 32000
#define D_ 512
#define N_ 16
#define R_ 512
#define G4_ 2048   // 4*R
#define SV_ 8192000 // S_*V_

typedef __attribute__((ext_vector_type(8))) short short8;
typedef __attribute__((ext_vector_type(4))) float f32x4;
typedef __attribute__((ext_vector_type(4))) unsigned short u16x4;
typedef __attribute__((ext_vector_type(4))) unsigned int u32x4;

__device__ __forceinline__ unsigned short f2b(float f){
  union { float f; unsigned int u; } v; v.f = f;
  unsigned int r = (v.u + 0x7fffu + ((v.u >> 16) & 1u)) >> 16;
  return (unsigned short)r;
}
__device__ __forceinline__ float b2f(unsigned short h){
  union { unsigned int u; float f; } v; v.u = ((unsigned int)h) << 16;
  return v.f;
}

// ---- permute+cast W_ih/W_hh rows: g = q*512+r  ->  g' = r*4+q (interleave gates) ----
__global__ void k_permute_cast(const float* __restrict__ src, unsigned short* __restrict__ dst,
                               const float* __restrict__ b1, const float* __restrict__ b2,
                               float* __restrict__ bias_out)
{
  int bid = blockIdx.x;              // n*2048+g
  int n = bid >> 11, g = bid & 2047;
  int q = g >> 9, r = g & 511;
  int gp = (r << 2) | q;
  const float* s = src + (size_t)bid * 512;
  unsigned short* d = dst + ((size_t)(n * 2048 + gp)) * 512;
  int l = threadIdx.x; // 64
  f32x4 a = ((const f32x4*)s)[l*2];
  f32x4 c = ((const f32x4*)s)[l*2+1];
  u16x4 o1, o2;
  o1[0]=f2b(a[0]); o1[1]=f2b(a[1]); o1[2]=f2b(a[2]); o1[3]=f2b(a[3]);
  o2[0]=f2b(c[0]); o2[1]=f2b(c[1]); o2[2]=f2b(c[2]); o2[3]=f2b(c[3]);
  ((u16x4*)d)[l*2] = o1; ((u16x4*)d)[l*2+1] = o2;
  if (l == 0 && bias_out) bias_out[n*2048 + gp] = b1[bid] + b2[bid];
}

// ---- plain fp32 -> bf16 cast, 8 elems/thread, exact grids ----
__global__ void k_cast(const float* __restrict__ src, unsigned short* __restrict__ dst)
{
  int i = blockIdx.x * 256 + threadIdx.x;
  f32x4 a = ((const f32x4*)src)[i*2];
  f32x4 c = ((const f32x4*)src)[i*2+1];
  u16x4 o1, o2;
  o1[0]=f2b(a[0]); o1[1]=f2b(a[1]); o1[2]=f2b(a[2]); o1[3]=f2b(a[3]);
  o2[0]=f2b(c[0]); o2[1]=f2b(c[1]); o2[2]=f2b(c[2]); o2[3]=f2b(c[3]);
  ((u16x4*)dst)[i*2] = o1; ((u16x4*)dst)[i*2+1] = o2;
}

// ---- transpose W_np [n][d][r] -> WnpT [n][r][d] (bf16 out), 64x64 tiles ----
__global__ void k_transpose_np(const float* __restrict__ src, unsigned short* __restrict__ dst)
{
  __shared__ float tile[64][65];
  int bid = blockIdx.x;                 // n*64 + dt*8 + rt
  int n = bid >> 6, dt = (bid >> 3) & 7, rt = bid & 7;
  int tid = threadIdx.x;
  int row = tid >> 2, c4 = (tid & 3) * 16;
  const float* s = src + ((size_t)n*512 + dt*64 + row)*512 + rt*64 + c4;
#pragma unroll
  for (int i = 0; i < 16; i += 4){
    f32x4 v = *(const f32x4*)(s + i);
    tile[row][c4+i] = v[0]; tile[row][c4+i+1] = v[1];
    tile[row][c4+i+2] = v[2]; tile[row][c4+i+3] = v[3];
  }
  __syncthreads();
  unsigned short* d = dst + ((size_t)n*512 + rt*64 + row)*512 + dt*64 + c4;
#pragma unroll
  for (int i = 0; i < 16; i += 4){
    u16x4 o;
    o[0]=f2b(tile[c4+i][row]);   o[1]=f2b(tile[c4+i+1][row]);
    o[2]=f2b(tile[c4+i+2][row]); o[3]=f2b(tile[c4+i+3][row]);
    *(u16x4*)(d + i) = o;
  }
}

// ---- transpose op_w [d][e] -> op_wT [e][d] fp32 ----
__global__ void k_transpose_op(const float* __restrict__ src, float* __restrict__ dst)
{
  __shared__ float tile[64][65];
  int bid = blockIdx.x; int dt = bid >> 3, et = bid & 7;
  int tid = threadIdx.x;
  int row = tid >> 2, c4 = (tid & 3) * 16;
  const float* s = src + ((size_t)(dt*64 + row))*512 + et*64 + c4;
#pragma unroll
  for (int i = 0; i < 16; i += 4){
    f32x4 v = *(const f32x4*)(s + i);
    tile[row][c4+i] = v[0]; tile[row][c4+i+1] = v[1];
    tile[row][c4+i+2] = v[2]; tile[row][c4+i+3] = v[3];
  }
  __syncthreads();
  float* d = dst + ((size_t)(et*64 + row))*512 + dt*64 + c4;
#pragma unroll
  for (int i = 0; i < 16; i++) d[i] = tile[c4+i][row];
}

// ---- embedding gather: xs[t][b][d] fp32 + bf16 copy ----
__global__ void k_embed(const int* __restrict__ x, const float* __restrict__ emb,
                        float* __restrict__ xs, unsigned short* __restrict__ xs_bf)
{
  int row = blockIdx.x;       // t*8+b
  int t = row >> 3, b = row & 7;
  int tok = x[b*S_ + t];
  const f32x4* e = (const f32x4*)(emb + (size_t)tok*512);
  int l = threadIdx.x; // 64
  f32x4 v0 = e[l*2], v1 = e[l*2+1];
  f32x4* xo = (f32x4*)(xs + (size_t)row*512);
  xo[l*2] = v0; xo[l*2+1] = v1;
  u16x4 o0, o1;
  o0[0]=f2b(v0[0]); o0[1]=f2b(v0[1]); o0[2]=f2b(v0[2]); o0[3]=f2b(v0[3]);
  o1[0]=f2b(v1[0]); o1[1]=f2b(v1[1]); o1[2]=f2b(v1[2]); o1[3]=f2b(v1[3]);
  u16x4* xb = (u16x4*)(xs_bf + (size_t)row*512);
  xb[l*2] = o0; xb[l*2+1] = o1;
}

// ---- init h/c state; h_bf has 2 buffers [16][16][512] with rows 8..15 zero ----
__global__ void k_init(const float* __restrict__ h0, const float* __restrict__ c0,
                       float* __restrict__ h_state, float* __restrict__ c_state,
                       unsigned short* __restrict__ h_bf)
{
  int i = blockIdx.x * 256 + threadIdx.x;
  if (i < 65536){
    float hv = h0[i], cv = c0[i];
    h_state[i] = hv; c_state[i] = cv;
    int n = i >> 12, b = (i >> 9) & 7, r = i & 511;
    unsigned short hb = f2b(hv);
    h_bf[((size_t)n*16 + b)*512 + r] = hb;
    h_bf[131072 + ((size_t)n*16 + b)*512 + r] = hb;
  } else {
    int j = i - 65536;           // < 131072 : pad rows of both buffers
    int buf = j >> 16, rem = j & 65535;
    int n = rem >> 12, pr = (rem >> 9) & 7, r = rem & 511;
    h_bf[(size_t)buf*131072 + ((size_t)n*16 + 8 + pr)*512 + r] = 0;
  }
}

// ---- generic 128x128-tile bf16 MFMA GEMM: C[m][col] = sum_k A[m][k]*B[col][k] + bias[col]
// MODE 0: gates chunk -> bf16 [t][n][g'][b] ; MODE 1: fp32 row-major ;
// MODE 2: head -> fp32 d_out [b][t][v] ; MODE 3: bf16 row-major
template<int MODE>
__global__ __launch_bounds__(256)
void k_gemm(const unsigned short* __restrict__ A, const unsigned short* __restrict__ Bm,
            const float* __restrict__ bias, void* __restrict__ Cout,
            int M, int Ncol, int ldc, int nblocks, long strideB, long strideC)
{
  __shared__ unsigned short lA[128*56];
  __shared__ unsigned short lB[128*56];
  const unsigned short* Bp = Bm + (size_t)blockIdx.y * strideB;
  int bid = blockIdx.x;
  int mb = bid / nblocks, nb = bid - mb*nblocks;
  int m0 = mb*128, n0 = nb*128;
  int tid = threadIdx.x;
  int wv = tid >> 6, lane = tid & 63;
  int quad = lane >> 4, l16 = lane & 15;
  int wm = wv & 1, wn = wv >> 1;
  f32x4 acc[4][4];
  f32x4 z = {0.f,0.f,0.f,0.f};
#pragma unroll
  for (int i=0;i<4;i++)
#pragma unroll
    for (int j=0;j<4;j++) acc[i][j] = z;

  int lrow = tid >> 2;
  int lkc  = (tid & 3) * 8;
  for (int k0 = 0; k0 < 512; k0 += 32){
    __syncthreads();
#pragma unroll
    for (int h = 0; h < 2; h++){
      int row = lrow + h*64;
      int ar = m0 + row; if (ar >= M) ar = M - 1;
      u32x4 va = *(const u32x4*)(A + (size_t)ar*512 + k0 + lkc);
      *(u32x4*)(lA + row*56 + lkc) = va;
      int br = n0 + row; if (br >= Ncol) br = Ncol - 1;
      u32x4 vb = *(const u32x4*)(Bp + (size_t)br*512 + k0 + lkc);
      *(u32x4*)(lB + row*56 + lkc) = vb;
    }
    __syncthreads();
    short8 af[4], bfr[4];
#pragma unroll
    for (int i=0;i<4;i++)
      af[i] = *(const short8*)(lA + (wm*64 + i*16 + l16)*56 + quad*8);
#pragma unroll
    for (int j=0;j<4;j++)
      bfr[j] = *(const short8*)(lB + (wn*64 + j*16 + l16)*56 + quad*8);
#pragma unroll
    for (int i=0;i<4;i++)
#pragma unroll
      for (int j=0;j<4;j++)
        acc[i][j] = __builtin_amdgcn_mfma_f32_16x16x32_bf16(af[i], bfr[j], acc[i][j], 0, 0, 0);
  }
  // epilogue
#pragma unroll
  for (int j = 0; j < 4; j++){
    int col = n0 + wn*64 + j*16 + l16;
    float bv = 0.0f;
    if (bias != nullptr && col < Ncol) bv = bias[col];
#pragma unroll
    for (int i = 0; i < 4; i++){
      int rbase = m0 + wm*64 + i*16 + quad*4;
      f32x4 v = acc[i][j];
      if (MODE == 0){
        int tt = rbase >> 3, b0 = rbase & 7;
        int nn = col >> 11, gp = col & 2047;
        u16x4 pk;
        pk[0]=f2b(v[0]+bv); pk[1]=f2b(v[1]+bv); pk[2]=f2b(v[2]+bv); pk[3]=f2b(v[3]+bv);
        *(u16x4*)((unsigned short*)Cout + (((size_t)tt*16 + nn)*2048 + (size_t)gp)*8 + b0) = pk;
      } else if (MODE == 1){
        float* O = (float*)Cout + (size_t)blockIdx.y * strideC;
#pragma unroll
        for (int r = 0; r < 4; r++){
          int m = rbase + r;
          if (m < M && col < Ncol) O[(size_t)m*ldc + col] = v[r] + bv;
        }
      } else if (MODE == 2){
        float* O = (float*)Cout;
#pragma unroll
        for (int r = 0; r < 4; r++){
          int m = rbase + r;
          int bb = m & 7, tt = m >> 3;
          O[(size_t)bb*SV_ + (size_t)tt*V_ + col] = v[r] + bv;
        }
      } else {
        unsigned short* O = (unsigned short*)Cout + (size_t)blockIdx.y * strideC;
#pragma unroll
        for (int r = 0; r < 4; r++){
          int m = rbase + r;
          if (m < M && col < Ncol) O[(size_t)m*ldc + col] = f2b(v[r] + bv);
        }
      }
    }
  }
}

// ---- per-step stage 1: gates = gates_in + h @ W_hh'  -> LSTM update ----
// grid 512 = n(16) * cb(32); each wave: one 16-col MFMA tile (16 g' = 4 r quadruples)
__global__ __launch_bounds__(256)
void k_lstm(const unsigned short* __restrict__ h_in, unsigned short* __restrict__ h_out,
            const unsigned short* __restrict__ gates_t, const unsigned short* __restrict__ W_hhp,
            float* __restrict__ h_state, float* __restrict__ c_state)
{
  __shared__ float gsh[4][8][18];
  int bid = blockIdx.x;
  int n = bid >> 5, cb = bid & 31;
  int tid = threadIdx.x, wv = tid >> 6, lane = tid & 63;
  int quad = lane >> 4, l16 = lane & 15;
  int gp0 = cb*64 + wv*16;
  const unsigned short* hA = h_in + (size_t)n*8192;
  const unsigned short* WB = W_hhp + ((size_t)n*2048 + gp0)*512;
  f32x4 acc = {0.f,0.f,0.f,0.f};
  if (quad < 2){
    u16x4 gv = *(const u16x4*)(gates_t + (((size_t)n*2048) + gp0 + l16)*8 + quad*4);
    acc[0]=b2f(gv[0]); acc[1]=b2f(gv[1]); acc[2]=b2f(gv[2]); acc[3]=b2f(gv[3]);
  }
#pragma unroll
  for (int k0 = 0; k0 < 512; k0 += 32){
    short8 af = *(const short8*)(hA + (size_t)l16*512 + k0 + quad*8);
    short8 bfr = *(const short8*)(WB + (size_t)l16*512 + k0 + quad*8);
    acc = __builtin_amdgcn_mfma_f32_16x16x32_bf16(af, bfr, acc, 0, 0, 0);
  }
  if (quad < 2){
#pragma unroll
    for (int r = 0; r < 4; r++) gsh[wv][quad*4+r][l16] = acc[r];
  }
  __syncthreads();
  if (lane < 32){
    int b = lane >> 2, rl = lane & 3;
    float gi = gsh[wv][b][rl*4+0];
    float gf = gsh[wv][b][rl*4+1];
    float gg = gsh[wv][b][rl*4+2];
    float go = gsh[wv][b][rl*4+3];
    int r = cb*16 + wv*4 + rl;
    size_t idx = ((size_t)n*8 + b)*512 + r;
    float c = c_state[idx];
    float si = 1.f/(1.f + expf(-gi));
    float sf = 1.f/(1.f + expf(-gf));
    float so = 1.f/(1.f + expf(-go));
    float cn = sf*c + si*tanhf(gg);
    float hn = so*tanhf(cn);
    c_state[idx] = cn;
    h_state[idx] = hn;
    h_out[((size_t)n*16 + b)*512 + r] = f2b(hn);
  }
}

// ---- per-step stage 2: kv[b][n][e'] = h @ A_kv[n]^T + bias_kv[n]  (e'<512:k, >=512:v) ----
__global__ __launch_bounds__(256)
void k_kv(const unsigned short* __restrict__ h_bf, const unsigned short* __restrict__ A_kv,
          const float* __restrict__ bias_kv, float* __restrict__ kv_ws)
{
  int bid = blockIdx.x;
  int n = bid >> 4, cb = bid & 15;
  int tid = threadIdx.x, wv = tid >> 6, lane = tid & 63;
  int quad = lane >> 4, l16 = lane & 15;
  int e0 = cb*64 + wv*16;
  const unsigned short* hA = h_bf + (size_t)n*8192;
  const unsigned short* WB = A_kv + ((size_t)n*1024 + e0)*512;
  float bv = bias_kv[n*1024 + e0 + l16];
  f32x4 acc = {bv, bv, bv, bv};
#pragma unroll
  for (int k0 = 0; k0 < 512; k0 += 32){
    short8 af = *(const short8*)(hA + (size_t)l16*512 + k0 + quad*8);
    short8 bfr = *(const short8*)(WB + (size_t)l16*512 + k0 + quad*8);
    acc = __builtin_amdgcn_mfma_f32_16x16x32_bf16(af, bfr, acc, 0, 0, 0);
  }
  if (quad < 2){
    int e = e0 + l16;
#pragma unroll
    for (int r = 0; r < 4; r++){
      int b = quad*4 + r;
      kv_ws[((size_t)b*16 + n)*1024 + e] = acc[r];
    }
  }
}

// ---- per-step stage 3: attention + op-proj + residual + LN -> mixed_bf[t*8+b][d] ----
__global__ __launch_bounds__(256)
void k_att(const float* __restrict__ kv_ws, const float* __restrict__ q_all,
           const float* __restrict__ xs, const float* __restrict__ op_wT,
           const float* __restrict__ op_b, const float* __restrict__ ln_g,
           const float* __restrict__ ln_b, unsigned short* __restrict__ mixed_bf, int t)
{
  __shared__ float sV[16][528];
  __shared__ float sQ[512];
  __shared__ float sS[8][16];
  __shared__ float sW[8][16];
  __shared__ float sA[512];
  __shared__ float sY[512];
  __shared__ float red[4];
  int b = blockIdx.x, tid = threadIdx.x;
  int wv = tid >> 6, lane = tid & 63;
#pragma unroll
  for (int c = tid; c < 2048; c += 256){
    int n = c >> 7, e4 = (c & 127) * 4;
    f32x4 v = *(const f32x4*)(kv_ws + ((size_t)b*16 + n)*1024 + 512 + e4);
    *(f32x4*)&sV[n][e4] = v;
  }
  if (tid < 128){
    f32x4 q4 = *(const f32x4*)(q_all + ((size_t)t*8 + b)*512 + tid*4);
    *(f32x4*)&sQ[tid*4] = q4;
  }
  __syncthreads();
  if (tid < 128){
    int h = tid >> 4, nn = tid & 15;
    const f32x4* kp = (const f32x4*)(kv_ws + ((size_t)b*16 + nn)*1024 + h*64);
    const f32x4* qp = (const f32x4*)(sQ + h*64);
    float s = 0.f;
#pragma unroll
    for (int i = 0; i < 16; i++){
      f32x4 k4 = kp[i], q4 = qp[i];
      s += k4[0]*q4[0] + k4[1]*q4[1] + k4[2]*q4[2] + k4[3]*q4[3];
    }
    sS[h][nn] = s * 0.125f;
  }
  __syncthreads();
  if (tid < 8){
    float mx = -1e30f;
#pragma unroll
    for (int nn = 0; nn < 16; nn++) mx = fmaxf(mx, sS[tid][nn]);
    float ex[16]; float sum = 0.f;
#pragma unroll
    for (int nn = 0; nn < 16; nn++){ ex[nn] = expf(sS[tid][nn] - mx); sum += ex[nn]; }
    float inv = 1.f/sum;
#pragma unroll
    for (int nn = 0; nn < 16; nn++) sW[tid][nn] = ex[nn]*inv;
  }
  __syncthreads();
#pragma unroll
  for (int d = tid; d < 512; d += 256){
    int h = d >> 6;
    float a = 0.f;
#pragma unroll
    for (int nn = 0; nn < 16; nn++) a += sW[h][nn] * sV[nn][d];
    sA[d] = a;
  }
  __syncthreads();
  float a0 = 0.f, a1 = 0.f;
  for (int e = 0; e < 512; e += 4){
    float w0 = sA[e], w1 = sA[e+1], w2 = sA[e+2], w3 = sA[e+3];
    const float* r0 = op_wT + (size_t)e*512 + tid;
    a0 += w0*r0[0]   + w1*r0[512] + w2*r0[1024] + w3*r0[1536];
    a1 += w0*r0[256] + w1*r0[768] + w2*r0[1280] + w3*r0[1792];
  }
  const float* xrow = xs + ((size_t)t*8 + b)*512;
  sY[tid]     = a0 + op_b[tid]     + xrow[tid];
  sY[tid+256] = a1 + op_b[tid+256] + xrow[tid+256];
  __syncthreads();
  float part = sY[tid] + sY[tid+256];
#pragma unroll
  for (int off = 32; off; off >>= 1) part += __shfl_down(part, off);
  if (lane == 0) red[wv] = part;
  __syncthreads();
  float mu = (red[0]+red[1]+red[2]+red[3]) * (1.0f/512.0f);
  __syncthreads();
  float d0 = sY[tid] - mu, d1 = sY[tid+256] - mu;
  float p2 = d0*d0 + d1*d1;
#pragma unroll
  for (int off = 32; off; off >>= 1) p2 += __shfl_down(p2, off);
  if (lane == 0) red[wv] = p2;
  __syncthreads();
  float var = (red[0]+red[1]+red[2]+red[3]) * (1.0f/512.0f);
  float rstd = rsqrtf(var + 1e-5f);
  unsigned short* mrow = mixed_bf + ((size_t)t*8 + b)*512;
  mrow[tid]     = f2b(d0 * rstd * ln_g[tid]     + ln_b[tid]);
  mrow[tid+256] = f2b(d1 * rstd * ln_g[tid+256] + ln_b[tid+256]);
}

extern "C" void kernel_launch(void* const* d_in, const int* in_sizes, int n_in,
                              void* d_out, int out_size, void* d_ws, size_t ws_size,
                              hipStream_t stream)
{
  const int*   x      = (const int*)  d_in[0];
  const float* h0     = (const float*)d_in[1];
  const float* c0     = (const float*)d_in[2];
  const float* emb    = (const float*)d_in[3];
  const float* W_ih   = (const float*)d_in[4];
  const float* b_ih   = (const float*)d_in[5];
  const float* W_hh   = (const float*)d_in[6];
  const float* b_hh   = (const float*)d_in[7];
  const float* W_np   = (const float*)d_in[8];
  const float* b_np   = (const float*)d_in[9];
  const float* in_w   = (const float*)d_in[10];
  const float* in_b   = (const float*)d_in[11];
  const float* op_w   = (const float*)d_in[12];
  const float* op_b   = (const float*)d_in[13];
  const float* ln_g   = (const float*)d_in[14];
  const float* ln_b   = (const float*)d_in[15];
  const float* head_w = (const float*)d_in[16];
  const float* head_b = (const float*)d_in[17];
  float* out = (float*)d_out;

  char* p = (char*)d_ws;
  unsigned short* gates_buf = (unsigned short*)p;         p += 33554432; // [64][16][2048][8] bf16
  unsigned short* WnpT      = (unsigned short*)gates_buf;                // alias: used only pre-loop
  unsigned short* W_ihp     = (unsigned short*)p;         p += 33554432;
  unsigned short* W_hhp     = (unsigned short*)p;         p += 33554432;
  unsigned short* headw_bf  = (unsigned short*)p;         p += 32768000;
  unsigned short* A_kv      = (unsigned short*)p;         p += 16777216;
  float*          xs        = (float*)p;                  p += 4194304;
  float*          q_all     = (float*)p;                  p += 4194304;
  unsigned short* mixed_bf  = (unsigned short*)p;         p += 2097152;
  unsigned short* xs_bf     = (unsigned short*)p;         p += 2097152;
  unsigned short* Wkv_bf    = (unsigned short*)p;         p += 1048576;
  unsigned short* Wq_bf     = (unsigned short*)p;         p += 524288;
  float*          op_wT     = (float*)p;                  p += 1048576;
  float*          kv_ws     = (float*)p;                  p += 524288;
  float*          h_state   = (float*)p;                  p += 262144;
  float*          c_state   = (float*)p;                  p += 262144;
  unsigned short* h_bf      = (unsigned short*)p;         p += 524288;  // 2 buffers
  float*          bias_g    = (float*)p;                  p += 131072;
  float*          bias_kvw  = (float*)p;                  p += 65536;
  unsigned short* bnp_bf    = (unsigned short*)p;         p += 16384;

  // ---- precompute ----
  k_permute_cast<<<32768, 64, 0, stream>>>(W_ih, W_ihp, b_ih, b_hh, bias_g);
  k_permute_cast<<<32768, 64, 0, stream>>>(W_hh, W_hhp, nullptr, nullptr, nullptr);
  k_cast<<<8000, 256, 0, stream>>>(head_w, headw_bf);
  k_cast<<<256, 256, 0, stream>>>(in_w + 512*512, Wkv_bf);   // rows 512..1535 (Wk||Wv)
  k_cast<<<128, 256, 0, stream>>>(in_w, Wq_bf);              // rows 0..511
  k_cast<<<4, 256, 0, stream>>>(b_np, bnp_bf);
  k_transpose_np<<<1024, 256, 0, stream>>>(W_np, WnpT);
  k_transpose_op<<<64, 256, 0, stream>>>(op_w, op_wT);
  // A_kv[n][e'][r] = sum_d Wkv[e'][d] * W_np[n][d][r]
  k_gemm<3><<<dim3(32, 16), 256, 0, stream>>>(Wkv_bf, WnpT, nullptr, A_kv,
                                              1024, 512, 512, 4, 262144L, 524288L);
  // bias_kv[n][e'] = sum_d b_np[n][d]*Wkv[e'][d] + in_b[512+e']
  k_gemm<1><<<dim3(8, 1), 256, 0, stream>>>(bnp_bf, Wkv_bf, in_b + 512, bias_kvw,
                                            16, 1024, 1024, 8, 0, 0);
  k_embed<<<2048, 64, 0, stream>>>(x, emb, xs, xs_bf);
  // q_all = xs @ Wq^T + bq
  k_gemm<1><<<dim3(64, 1), 256, 0, stream>>>(xs_bf, Wq_bf, in_b, q_all,
                                             2048, 512, 512, 4, 0, 0);
  k_init<<<768, 256, 0, stream>>>(h0, c0, h_state, c_state, h_bf);

  // ---- sequential recurrence ----
  for (int t = 0; t < S_; t++){
    if ((t & 63) == 0){
      // gates_in for steps [t, t+64): (512 x 32768 x 512) bf16 GEMM
      k_gemm<0><<<dim3(1024, 1), 256, 0, stream>>>(xs_bf + (size_t)t*8*512, W_ihp, bias_g,
                                                   gates_buf, 512, 32768, 0, 256, 0, 0);
    }
    const unsigned short* hin = h_bf + (size_t)(t & 1) * 131072;
    unsigned short* hout = (unsigned short*)(h_bf + (size_t)((t + 1) & 1) * 131072);
    k_lstm<<<512, 256, 0, stream>>>(hin, hout,
                                    gates_buf + (size_t)(t & 63)*16*2048*8,
                                    W_hhp, h_state, c_state);
    k_kv<<<256, 256, 0, stream>>>(hout, A_kv, bias_kvw, kv_ws);
    k_att<<<8, 256, 0, stream>>>(kv_ws, q_all, xs, op_wT, op_b, ln_g, ln_b, mixed_bf, t);
  }

  // ---- head GEMM: logits[b][t][v] ----
  k_gemm<2><<<dim3(4000, 1), 256, 0, stream>>>(mixed_bf, headw_bf, head_b, out,
                                               2048, 32000, 0, 250, 0, 0);
  // ---- hf, cf ----
  hipMemcpyAsync(out + (size_t)B_*SV_,         h_state, 65536*sizeof(float),
                 hipMemcpyDeviceToDevice, stream);
  hipMemcpyAsync(out + (size_t)B_*SV_ + 65536, c_state, 65536*sizeof(float),
                 hipMemcpyDeviceToDevice, stream);
}